// Round 16
// baseline (6688.705 us; speedup 1.0000x reference)
//
#include <hip/hip_runtime.h>

#define NBATCH 32
#define NPTS   100000
#define NDIM   6
#define KSEL   1024
#define BPB    8                  // blocks per batch
#define NTHREADS 1024
#define TOTT   (BPB * NTHREADS)   // 8192 threads per batch
#define PPT    13                 // ceil(NPTS / TOTT)
#define MASK51 ((1ull << 51) - 1)

// Single-leg exchange (R15-proven): per block, TWO self-validating words
// (13b tag | 51b payload): w0 = tag<<51 | dist[62:12]; w1 = tag<<51 |
// dist[11:0]<<17 | idx17. Relaxed SYSTEM-scope only; no flags, no fences.
// R16 changes (structure, not protocol): ALL 16 waves poll/assemble/gather
// independently (kills 2nd barrier + LDS broadcast + 15-wave idle tail),
// and the poll is double-pumped (2 loads in flight halve the poll period).
struct Ws {
    unsigned long long w[2][NBATCH][16];   // 8 KB; 16 words = 2 lines per batch/parity
};

__global__ void __launch_bounds__(1024) fps_init(unsigned long long* w) {
    int i = blockIdx.x * blockDim.x + threadIdx.x;
    if (i < (int)(sizeof(Ws) / 8)) w[i] = 0ull;
}

__global__ void __launch_bounds__(NTHREADS, 1) fps_main(const float* __restrict__ pts,
                                                        float* __restrict__ out,
                                                        Ws* __restrict__ ws)
{
#pragma clang fp contract(off)
    const int bid   = blockIdx.x;
    const int batch = bid & (NBATCH - 1);
    const int blk   = bid >> 5;             // 0..7 within batch
    const int tid   = threadIdx.x;
    const int lane  = tid & 63;
    const int wav   = tid >> 6;             // 0..15
    const int tg    = blk * NTHREADS + tid; // 0..8191 within batch

    __shared__ double rdv[16];
    __shared__ int    rii[16];
    __shared__ int    idx_l[KSEL];          // leader (blk==0) only
    __shared__ double fr0[16], fr1[16], fr2[16];
    __shared__ double sc[4];

    const float* base = pts + (size_t)batch * NPTS * NDIM;

    // ---- point state in registers; dist in f64 (bit-exact vs numpy f64 FPS)
    float  px[PPT], py[PPT], pz[PPT];
    double pd[PPT];
#pragma unroll
    for (int k = 0; k < PPT; ++k) {
        int gi = k * TOTT + tg;
        if (gi < NPTS) {
            const float* p = base + (size_t)gi * NDIM;
            px[k] = p[0]; py[k] = p[1]; pz[k] = p[2];
            pd[k] = 1e10;
        } else {
            px[k] = 0.f; py[k] = 0.f; pz[k] = 0.f;
            pd[k] = -1.0;   // never wins (valid dists >= 0)
        }
    }

    double lx = (double)base[0], ly = (double)base[1], lz = (double)base[2]; // first = idx 0

    for (int t = 0; t < KSEL - 1; ++t) {
        const unsigned long long tag = (unsigned long long)(t + 1);   // <= 1023, fits 13b
        const int par = t & 1;
        // ---- f64 distance update + thread-local argmax (numpy order: (xx+yy)+zz, no FMA)
        double bd = -1.0; int bi = 0x7FFFFFFF;
#pragma unroll
        for (int k = 0; k < PPT; ++k) {
            double dx = (double)px[k] - lx;
            double dy = (double)py[k] - ly;
            double dz = (double)pz[k] - lz;
            double dd = ((dx * dx) + (dy * dy)) + (dz * dz);
            double nd = fmin(pd[k], dd);
            pd[k] = nd;
            if (nd > bd) { bd = nd; bi = k * TOTT + tg; }  // strict >: first max in-thread
        }
        // ---- wave reduce (dist desc, idx asc)
#pragma unroll
        for (int off = 32; off >= 1; off >>= 1) {
            double od = __shfl_xor(bd, off, 64);
            int    oi = __shfl_xor(bi, off, 64);
            if (od > bd || (od == bd && oi < bi)) { bd = od; bi = oi; }
        }
        if (lane == 0) { rdv[wav] = bd; rii[wav] = bi; }
        __syncthreads();   // the ONLY barrier per iteration

        // ---- ALL waves: block reduce over the 16 wave winners (lanes 0..15)
        double qd = (lane < 16) ? rdv[lane] : -2.0;
        int    qi = (lane < 16) ? rii[lane] : 0x7FFFFFFF;
#pragma unroll
        for (int off = 8; off >= 1; off >>= 1) {
            double od = __shfl_xor(qd, off, 64);
            int    oi = __shfl_xor(qi, off, 64);
            if (od > qd || (od == qd && oi < qi)) { qd = od; qi = oi; }
        }
        // ---- post: wave0 lanes 0..1 fire the two self-validating words (no fence)
        unsigned long long* brow = &ws->w[par][batch][0];
        if (wav == 0 && lane < 2) {
            unsigned long long db = (unsigned long long)__double_as_longlong(qd); // bit63==0
            unsigned long long w0 = (tag << 51) | (db >> 12);
            unsigned long long w1 = (tag << 51) | ((db & 0xFFFull) << 17)
                                  | (unsigned long long)(unsigned)qi;
            __hip_atomic_store(&brow[blk * 2 + lane], (lane == 0) ? w0 : w1,
                               __ATOMIC_RELAXED, __HIP_MEMORY_SCOPE_SYSTEM);
        }
        // ---- every wave polls independently (lanes 0..15), double-pumped
        unsigned long long vcur = 0ull, vnxt = 0ull;
        if (lane < 16)
            vcur = __hip_atomic_load(&brow[lane], __ATOMIC_RELAXED, __HIP_MEMORY_SCOPE_SYSTEM);
        for (;;) {
            if (lane < 16)
                vnxt = __hip_atomic_load(&brow[lane], __ATOMIC_RELAXED, __HIP_MEMORY_SCOPE_SYSTEM);
            int ok = (lane < 16) ? ((vcur >> 51) == tag) : 1;
            if (__all(ok)) break;          // vcur is tagged => payload valid (self-validating)
            vcur = vnxt;
        }
        // ---- assemble per-block records (block b -> lanes with lane&7 == b) and reduce
        unsigned long long p0 = __shfl(vcur, (lane & 7) * 2,     64) & MASK51;
        unsigned long long p1 = __shfl(vcur, (lane & 7) * 2 + 1, 64) & MASK51;
        unsigned long long rdb = (p0 << 12) | (p1 >> 17);
        int ridx = (int)(p1 & 0x1FFFFull);
#pragma unroll
        for (int off = 4; off >= 1; off >>= 1) {   // u64 compare == f64 compare (nonneg)
            unsigned long long od = __shfl_xor(rdb, off, 64);
            int                oi = __shfl_xor(ridx, off, 64);
            if (od > rdb || (od == rdb && oi < ridx)) { rdb = od; ridx = oi; }
        }
        if (blk == 0 && tid == 0) idx_l[t + 1] = ridx;
        // ---- every lane gathers winner xyz (same addr -> broadcast-coalesced; pts read-only)
        const float* wp = base + (size_t)ridx * NDIM;
        lx = (double)wp[0]; ly = (double)wp[1]; lz = (double)wp[2];
    }

    if (blk != 0) return;

    // ============ epilogue (leader block per batch): gather + normalize, f64 accumulation ============
    if (tid == 0) idx_l[0] = 0;
    __syncthreads();

    int si = idx_l[tid];
    const float* sp = base + (size_t)si * NDIM;
    float sx = sp[0], sy = sp[1], szv = sp[2];
    float f3 = sp[3], f4 = sp[4], f5 = sp[5];

    double rx = (double)sx, ry = (double)sy, rz = (double)szv;
#pragma unroll
    for (int off = 32; off >= 1; off >>= 1) {
        rx += __shfl_xor(rx, off, 64);
        ry += __shfl_xor(ry, off, 64);
        rz += __shfl_xor(rz, off, 64);
    }
    if (lane == 0) { fr0[wav] = rx; fr1[wav] = ry; fr2[wav] = rz; }
    __syncthreads();
    if (tid == 0) {
        double tx = 0., ty = 0., tz = 0.;
        for (int i = 0; i < 16; ++i) { tx += fr0[i]; ty += fr1[i]; tz += fr2[i]; }
        sc[0] = tx / (double)KSEL; sc[1] = ty / (double)KSEL; sc[2] = tz / (double)KSEL;
    }
    __syncthreads();
    double ax = (double)sx - sc[0], ay = (double)sy - sc[1], az = (double)szv - sc[2];
    double m = fmax(fabs(ax), fmax(fabs(ay), fabs(az)));
#pragma unroll
    for (int off = 32; off >= 1; off >>= 1) {
        double om = __shfl_xor(m, off, 64);
        m = fmax(m, om);
    }
    if (lane == 0) fr0[wav] = m;
    __syncthreads();
    if (tid == 0) {
        double mm = 0.;
        for (int i = 0; i < 16; ++i) mm = fmax(mm, fr0[i]);
        sc[3] = fmax(mm, 1e-6);
    }
    __syncthreads();
    double scale = sc[3];

    float* ob = out + ((size_t)batch * KSEL + tid) * NDIM;
    ob[0] = (float)(ax / scale);
    ob[1] = (float)(ay / scale);
    ob[2] = (float)(az / scale);
    ob[3] = f3; ob[4] = f4; ob[5] = f5;
}

extern "C" void kernel_launch(void* const* d_in, const int* in_sizes, int n_in,
                              void* d_out, int out_size, void* d_ws, size_t ws_size,
                              hipStream_t stream)
{
    const float* pts = (const float*)d_in[0];
    float* out = (float*)d_out;
    Ws* ws = (Ws*)d_ws;

    // re-zero slot words every call (graph replays must not see stale tags)
    hipLaunchKernelGGL(fps_init, dim3(1), dim3(1024), 0, stream, (unsigned long long*)d_ws);

    void* args[] = { (void*)&pts, (void*)&out, (void*)&ws };
    hipLaunchCooperativeKernel((void*)fps_main, dim3(NBATCH * BPB), dim3(NTHREADS),
                               args, 0, stream);
}

// Round 17
// 3531.030 us; speedup vs baseline: 1.8943x; 1.8943x over previous
//
#include <hip/hip_runtime.h>

#define NBATCH 32
#define NPTS   100000
#define NDIM   6
#define KSEL   1024
#define BPB    8                  // blocks per batch
#define NTHREADS 1024
#define TOTT   (BPB * NTHREADS)   // 8192 threads per batch
#define PPT    13                 // ceil(NPTS / TOTT)
#define MASK51 ((1ull << 51) - 1)

// Single-leg exchange (R15-proven, best at 3.94 ms): per block TWO
// self-validating words (13b tag | 51b payload); relaxed SYSTEM scope, no
// fences, wave0-only poll (R16 proved all-wave polling congests the home
// node: 16x traffic -> +70% time). R17 adds ONLY an f32 screen in compute.
struct Ws {
    unsigned long long w[2][NBATCH][16];   // 8 KB; 16 words = 2 lines per batch/parity
};

__global__ void __launch_bounds__(1024) fps_init(unsigned long long* w) {
    int i = blockIdx.x * blockDim.x + threadIdx.x;
    if (i < (int)(sizeof(Ws) / 8)) w[i] = 0ull;
}

__global__ void __launch_bounds__(NTHREADS, 1) fps_main(const float* __restrict__ pts,
                                                        float* __restrict__ out,
                                                        Ws* __restrict__ ws)
{
#pragma clang fp contract(off)
    const int bid   = blockIdx.x;
    const int batch = bid & (NBATCH - 1);
    const int blk   = bid >> 5;             // 0..7 within batch
    const int tid   = threadIdx.x;
    const int lane  = tid & 63;
    const int wav   = tid >> 6;             // 0..15
    const int tg    = blk * NTHREADS + tid; // 0..8191 within batch

    __shared__ double rdv[16];
    __shared__ int    rii[16];
    __shared__ float  lsh[3];               // broadcast winner xyz
    __shared__ int    idx_l[KSEL];          // leader (blk==0) only
    __shared__ double fr0[16], fr1[16], fr2[16];
    __shared__ double sc[4];

    const float* base = pts + (size_t)batch * NPTS * NDIM;

    // ---- point state in registers; dist in f64 (bit-exact vs numpy f64 FPS).
    // NO new persistent arrays (R10 lesson: +13 regs -> memory-backed spill).
    float  px[PPT], py[PPT], pz[PPT];
    double pd[PPT];
#pragma unroll
    for (int k = 0; k < PPT; ++k) {
        int gi = k * TOTT + tg;
        if (gi < NPTS) {
            const float* p = base + (size_t)gi * NDIM;
            px[k] = p[0]; py[k] = p[1]; pz[k] = p[2];
            pd[k] = 1e10;
        } else {
            px[k] = 0.f; py[k] = 0.f; pz[k] = 0.f;
            pd[k] = -1.0;   // never wins (valid dists >= 0); screen always skips
        }
    }

    float  lxf = base[0], lyf = base[1], lzf = base[2];         // winner coords (exact f32)
    double lx = (double)lxf, ly = (double)lyf, lz = (double)lzf; // first = idx 0

    for (int t = 0; t < KSEL - 1; ++t) {
        const unsigned long long tag = (unsigned long long)(t + 1);   // <= 1023, fits 13b
        const int par = t & 1;
        // ---- f32 screen + exact f64 update + thread-local argmax.
        // Skip iff ddf > pdf*1.0001 -> provably dd_f64 > pd_f64 (rel err of
        // screen <= ~4e-7 << 1e-4 margin) -> min unchanged -> bit-exact.
        double bd = -1.0; int bi = 0x7FFFFFFF;
#pragma unroll
        for (int k = 0; k < PPT; ++k) {
            float dxf = px[k] - lxf;
            float dyf = py[k] - lyf;
            float dzf = pz[k] - lzf;
            float ddf = __fmaf_rn(dzf, dzf, __fmaf_rn(dyf, dyf, dxf * dxf));
            double nd = pd[k];
            if (!(ddf > (float)nd * 1.0001f)) {
                // exact f64 path (numpy order: (xx+yy)+zz, no FMA)
                double dx = (double)px[k] - lx;
                double dy = (double)py[k] - ly;
                double dz = (double)pz[k] - lz;
                double dd = ((dx * dx) + (dy * dy)) + (dz * dz);
                nd = fmin(nd, dd);
                pd[k] = nd;
            }
            if (nd > bd) { bd = nd; bi = k * TOTT + tg; }  // strict >: first max in-thread
        }
        // ---- wave reduce (dist desc, idx asc)
#pragma unroll
        for (int off = 32; off >= 1; off >>= 1) {
            double od = __shfl_xor(bd, off, 64);
            int    oi = __shfl_xor(bi, off, 64);
            if (od > bd || (od == bd && oi < bi)) { bd = od; bi = oi; }
        }
        if (lane == 0) { rdv[wav] = bd; rii[wav] = bi; }
        __syncthreads();

        if (wav == 0) {
            // ---- block reduce over 16 wave winners (lanes 0..15 hold them)
            double qd = (lane < 16) ? rdv[lane] : -2.0;
            int    qi = (lane < 16) ? rii[lane] : 0x7FFFFFFF;
#pragma unroll
            for (int off = 8; off >= 1; off >>= 1) {
                double od = __shfl_xor(qd, off, 64);
                int    oi = __shfl_xor(qi, off, 64);
                if (od > qd || (od == qd && oi < qi)) { qd = od; qi = oi; }
            }
            // ---- post: lanes 0..1 fire the two self-validating words (no fence)
            unsigned long long db = (unsigned long long)__double_as_longlong(qd); // bit63==0
            unsigned long long w0 = (tag << 51) | (db >> 12);
            unsigned long long w1 = (tag << 51) | ((db & 0xFFFull) << 17)
                                  | (unsigned long long)(unsigned)qi;
            unsigned long long* brow = &ws->w[par][batch][0];
            if (lane < 2)
                __hip_atomic_store(&brow[blk * 2 + lane], (lane == 0) ? w0 : w1,
                                   __ATOMIC_RELAXED, __HIP_MEMORY_SCOPE_SYSTEM);
            // ---- poll: 16 lanes, one word each; payload arrives WITH detection
            unsigned long long v = 0ull;
            for (;;) {
                if (lane < 16)
                    v = __hip_atomic_load(&brow[lane], __ATOMIC_RELAXED, __HIP_MEMORY_SCOPE_SYSTEM);
                int ok = (lane < 16) ? ((v >> 51) == tag) : 1;
                if (__all(ok)) break;
            }
            // ---- assemble per-block records into lanes (block b -> lanes with lane&7 == b)
            unsigned long long p0 = __shfl(v, (lane & 7) * 2,     64) & MASK51;
            unsigned long long p1 = __shfl(v, (lane & 7) * 2 + 1, 64) & MASK51;
            unsigned long long rdb = (p0 << 12) | (p1 >> 17);
            int ridx = (int)(p1 & 0x1FFFFull);
            // ---- reduce 8 blocks: u64 compare == f64 compare for nonneg dists
#pragma unroll
            for (int off = 4; off >= 1; off >>= 1) {
                unsigned long long od = __shfl_xor(rdb, off, 64);
                int                oi = __shfl_xor(ridx, off, 64);
                if (od > rdb || (od == rdb && oi < ridx)) { rdb = od; ridx = oi; }
            }
            if (lane == 0) {
                const float* wp = base + (size_t)ridx * NDIM;   // read-only, local-L2 resident
                lsh[0] = wp[0]; lsh[1] = wp[1]; lsh[2] = wp[2];
                if (blk == 0) idx_l[t + 1] = ridx;
            }
        }
        __syncthreads();
        lxf = lsh[0]; lyf = lsh[1]; lzf = lsh[2];
        lx = (double)lxf; ly = (double)lyf; lz = (double)lzf;
    }

    if (blk != 0) return;

    // ============ epilogue (leader block per batch): gather + normalize, f64 accumulation ============
    if (tid == 0) idx_l[0] = 0;
    __syncthreads();

    int si = idx_l[tid];
    const float* sp = base + (size_t)si * NDIM;
    float sx = sp[0], sy = sp[1], szv = sp[2];
    float f3 = sp[3], f4 = sp[4], f5 = sp[5];

    double rx = (double)sx, ry = (double)sy, rz = (double)szv;
#pragma unroll
    for (int off = 32; off >= 1; off >>= 1) {
        rx += __shfl_xor(rx, off, 64);
        ry += __shfl_xor(ry, off, 64);
        rz += __shfl_xor(rz, off, 64);
    }
    if (lane == 0) { fr0[wav] = rx; fr1[wav] = ry; fr2[wav] = rz; }
    __syncthreads();
    if (tid == 0) {
        double tx = 0., ty = 0., tz = 0.;
        for (int i = 0; i < 16; ++i) { tx += fr0[i]; ty += fr1[i]; tz += fr2[i]; }
        sc[0] = tx / (double)KSEL; sc[1] = ty / (double)KSEL; sc[2] = tz / (double)KSEL;
    }
    __syncthreads();
    double ax = (double)sx - sc[0], ay = (double)sy - sc[1], az = (double)szv - sc[2];
    double m = fmax(fabs(ax), fmax(fabs(ay), fabs(az)));
#pragma unroll
    for (int off = 32; off >= 1; off >>= 1) {
        double om = __shfl_xor(m, off, 64);
        m = fmax(m, om);
    }
    if (lane == 0) fr0[wav] = m;
    __syncthreads();
    if (tid == 0) {
        double mm = 0.;
        for (int i = 0; i < 16; ++i) mm = fmax(mm, fr0[i]);
        sc[3] = fmax(mm, 1e-6);
    }
    __syncthreads();
    double scale = sc[3];

    float* ob = out + ((size_t)batch * KSEL + tid) * NDIM;
    ob[0] = (float)(ax / scale);
    ob[1] = (float)(ay / scale);
    ob[2] = (float)(az / scale);
    ob[3] = f3; ob[4] = f4; ob[5] = f5;
}

extern "C" void kernel_launch(void* const* d_in, const int* in_sizes, int n_in,
                              void* d_out, int out_size, void* d_ws, size_t ws_size,
                              hipStream_t stream)
{
    const float* pts = (const float*)d_in[0];
    float* out = (float*)d_out;
    Ws* ws = (Ws*)d_ws;

    // re-zero slot words every call (graph replays must not see stale tags)
    hipLaunchKernelGGL(fps_init, dim3(1), dim3(1024), 0, stream, (unsigned long long*)d_ws);

    void* args[] = { (void*)&pts, (void*)&out, (void*)&ws };
    hipLaunchCooperativeKernel((void*)fps_main, dim3(NBATCH * BPB), dim3(NTHREADS),
                               args, 0, stream);
}